// Round 1
// baseline (535.734 us; speedup 1.0000x reference)
//
#include <hip/hip_runtime.h>
#include <cstddef>

// Problem constants (MemoryBank): H (B, DIM, T) f32, units (DIM, SIZE) f32
// out (B, SIZE, T) f32 = softmax_s(2*H^t.units - ||units||^2), transposed store.
constexpr int kB  = 32;
constexpr int kD  = 128;
constexpr int kT  = 4096;
constexpr int kS  = 512;
constexpr int kTT = 16;   // t-values per block

// ---------- prep: m2[s] = sum_d units[d][s]^2 (exact fp32) ----------
__global__ void m2_prep(const float* __restrict__ units, float* __restrict__ m2) {
    int s = blockIdx.x * 256 + threadIdx.x;   // grid 2x256 covers 512 exactly
    float acc = 0.f;
#pragma unroll 8
    for (int d = 0; d < kD; ++d) {
        float u = units[d * kS + s];
        acc = fmaf(u, u, acc);
    }
    m2[s] = acc;
}

// ---------- main ----------
// block: 256 threads, handles b = blockIdx.y, t in [t0, t0+16)
// thread: accumulates 16 t-rows x 2 s-cols (s = tid, tid+256) over K=128
__global__ __launch_bounds__(256, 3)
void mb_kernel(const float* __restrict__ H, const float* __restrict__ units,
               const float* __restrict__ m2, float* __restrict__ out) {
    __shared__ __align__(16) float Hs[kD * kTT];        // 8 KB, [d][i] = d*16+i
    __shared__ __align__(16) float Ls[kTT][kS + 1];     // 16*513*4 = 32.8 KB
    __shared__ float red[16 * 16];
    __shared__ float rowM[kTT];
    __shared__ float rowInv[kTT];

    const int tid = threadIdx.x;
    const int t0  = blockIdx.x * kTT;
    const int b   = blockIdx.y;

    // ---- stage H tile: Hs[d][i] = H[b][d][t0+i] ----
    {
        const float* Hb = H + (size_t)b * kD * kT + t0;
#pragma unroll
        for (int k = 0; k < (kD * kTT) / 256; ++k) {      // 8 iters
            int idx = tid + k * 256;
            int d = idx >> 4;          // /16
            int i = idx & 15;
            Hs[idx] = Hb[(size_t)d * kT + i];             // Hs layout == idx
        }
    }
    __syncthreads();

    // ---- fp32 GEMV block: acc[t][2] ----
    float acc0[kTT], acc1[kTT];
#pragma unroll
    for (int i = 0; i < kTT; ++i) { acc0[i] = 0.f; acc1[i] = 0.f; }
    const float* u0p = units + tid;
    const float* u1p = units + tid + 256;
#pragma unroll 2
    for (int d = 0; d < kD; ++d) {
        float u0 = u0p[d * kS];
        float u1 = u1p[d * kS];
        const float* hrow = &Hs[d * kTT];
#pragma unroll
        for (int i = 0; i < kTT; ++i) {
            float h = hrow[i];                            // wave-broadcast LDS read
            acc0[i] = fmaf(h, u0, acc0[i]);
            acc1[i] = fmaf(h, u1, acc1[i]);
        }
    }

    // ---- logits -> LDS (h^2 term cancels in softmax; logit = 2c - m2) ----
    const float mm0 = m2[tid];
    const float mm1 = m2[tid + 256];
#pragma unroll
    for (int i = 0; i < kTT; ++i) {
        Ls[i][tid]       = fmaf(2.f, acc0[i], -mm0);
        Ls[i][tid + 256] = fmaf(2.f, acc1[i], -mm1);
    }
    __syncthreads();

    // ---- softmax over s=512 per row. r = tid&15 row, j = tid>>4 chunk of 32 ----
    const int r = tid & 15;
    const int j = tid >> 4;                               // 0..15
    float* Lrow = &Ls[r][j * 32];
    float m = -3.0e38f;
#pragma unroll 8
    for (int k = 0; k < 32; ++k) m = fmaxf(m, Lrow[k]);
    red[j * 16 + r] = m;
    __syncthreads();
    if (tid < 16) {
        float mm = red[tid];
#pragma unroll
        for (int k = 1; k < 16; ++k) mm = fmaxf(mm, red[k * 16 + tid]);
        rowM[tid] = mm;
    }
    __syncthreads();
    const float M = rowM[r];
    float ssum = 0.f;
#pragma unroll 4
    for (int k = 0; k < 32; ++k) {
        float e = __expf(Lrow[k] - M);
        Lrow[k] = e;                                      // store exp in place
        ssum += e;
    }
    red[j * 16 + r] = ssum;
    __syncthreads();
    if (tid < 16) {
        float s = 0.f;
#pragma unroll
        for (int k = 0; k < 16; ++k) s += red[k * 16 + tid];
        rowInv[tid] = 1.f / s;
    }
    __syncthreads();

    // ---- transposed write: out[b][s][t0+i], float4 over i ----
    const int i4    = (tid & 3) * 4;                      // i base 0..12
    const int sBase = tid >> 2;                           // 0..63
    const float inv0 = rowInv[i4 + 0];
    const float inv1 = rowInv[i4 + 1];
    const float inv2 = rowInv[i4 + 2];
    const float inv3 = rowInv[i4 + 3];
    float* outB = out + ((size_t)b * kS) * kT + t0;
#pragma unroll
    for (int w = 0; w < 8; ++w) {
        int s = sBase + w * 64;
        float4 v;
        v.x = Ls[i4 + 0][s] * inv0;
        v.y = Ls[i4 + 1][s] * inv1;
        v.z = Ls[i4 + 2][s] * inv2;
        v.w = Ls[i4 + 3][s] * inv3;
        *(float4*)(outB + (size_t)s * kT + i4) = v;
    }
}

extern "C" void kernel_launch(void* const* d_in, const int* in_sizes, int n_in,
                              void* d_out, int out_size, void* d_ws, size_t ws_size,
                              hipStream_t stream) {
    const float* H     = (const float*)d_in[0];
    const float* units = (const float*)d_in[1];
    float* out = (float*)d_out;
    float* m2  = (float*)d_ws;                            // 512 floats of scratch

    m2_prep<<<dim3(2), dim3(256), 0, stream>>>(units, m2);
    dim3 grid(kT / kTT, kB);                              // 256 x 32 = 8192 blocks
    mb_kernel<<<grid, dim3(256), 0, stream>>>(H, units, m2, out);
}

// Round 3
// 390.758 us; speedup vs baseline: 1.3710x; 1.3710x over previous
//
#include <hip/hip_runtime.h>
#include <cstddef>

// MemoryBank: H (B=32, D=128, T=4096) f32, units (D=128, S=512) f32
// out (B, S, T) f32 = softmax_s(2*H^t.units - ||units||^2), transposed store.
// h^2 term cancels in the softmax. Cross term via split-bf16 MFMA:
//   x = hi + lo (bf16 each);  h.u ~= hh*uh + hl*uh + hh*ul  (drop lo*lo, ~1e-5 rel)
constexpr int kB  = 32;
constexpr int kD  = 128;
constexpr int kT  = 4096;
constexpr int kS  = 512;
constexpr int kMT = 32;    // t-rows per block
constexpr int kLsStride = 516;  // 512 + 4 pad: (16*q*516)%32 = 16q -> 2-way (free)

typedef __attribute__((ext_vector_type(8))) short bf16x8;   // 8 bf16 = 4 VGPRs
typedef __attribute__((ext_vector_type(4))) float f32x4;

__device__ __forceinline__ void split_bf16(float x, short& hi, short& lo) {
    union { float f; unsigned u; } a; a.f = x;
    unsigned r = (a.u + 0x7FFFu + ((a.u >> 16) & 1u)) & 0xFFFF0000u;  // RTN-even
    union { unsigned u; float f; } h; h.u = r;
    hi = (short)(r >> 16);
    float res = x - h.f;
    union { float f; unsigned u; } c; c.f = res;
    lo = (short)((c.u + 0x7FFFu + ((c.u >> 16) & 1u)) >> 16);
}

// ---------- prep: swizzle units into MFMA B-fragment order (hi/lo) + m2 ----------
// B-frag layout: idx = ((nt*4 + kk)*64 + lane)*8 + j
//   k = kk*32 + (lane>>4)*8 + j, n = nt*16 + (lane&15), value = units[k][n]
__global__ void prep_kernel(const float* __restrict__ units,
                            short* __restrict__ Bhi, short* __restrict__ Blo,
                            float* __restrict__ m2) {
    const int blk = blockIdx.x, tid = threadIdx.x;
    if (blk < 256) {
        int idx  = blk * 256 + tid;
        int j    = idx & 7;
        int lane = (idx >> 3) & 63;
        int kk   = (idx >> 9) & 3;
        int nt   = idx >> 11;
        int k = kk * 32 + (lane >> 4) * 8 + j;
        int n = nt * 16 + (lane & 15);
        float u = units[k * kS + n];
        short h, l; split_bf16(u, h, l);
        Bhi[idx] = h; Blo[idx] = l;
    } else {
        for (int s = tid; s < kS; s += 256) {
            float acc = 0.f;
#pragma unroll 8
            for (int d = 0; d < kD; ++d) {
                float u = units[d * kS + s];
                acc = fmaf(u, u, acc);
            }
            m2[s] = acc;
        }
    }
}

// ---------- main: block = 4 waves, 32 t-rows x 512 s, K=128 ----------
__global__ __launch_bounds__(256, 2)
void mb_mfma(const float* __restrict__ H,
             const short* __restrict__ Bhi, const short* __restrict__ Blo,
             const float* __restrict__ m2, float* __restrict__ out) {
    __shared__ float Ls[kMT][kLsStride];    // 66 KB logits->exp
    __shared__ float red[8 * 32];
    __shared__ float rowM[kMT];
    __shared__ float rowInv[kMT];

    const int tid  = threadIdx.x;
    const int wave = tid >> 6;
    const int lane = tid & 63;
    const int q    = lane >> 4;
    const int nl   = lane & 15;
    const int t0   = blockIdx.x * kMT;
    const int b    = blockIdx.y;

    // ---- A fragments straight from global: A[m][k] = H[b][k][t0+m] ----
    // lane holds m = mt*16+nl, k = kk*32 + q*8 + j (j=0..7). All 4 waves load
    // the same fragments (L1/L2-hot, 128B lines cover both mtiles).
    bf16x8 Ahi[2][4], Alo[2][4];
    {
        const float* Hb = H + ((size_t)b * kD) * kT + t0;
#pragma unroll
        for (int mt = 0; mt < 2; ++mt) {
            const int m = mt * 16 + nl;
#pragma unroll
            for (int kk = 0; kk < 4; ++kk) {
#pragma unroll
                for (int j = 0; j < 8; ++j) {
                    float x = Hb[(size_t)(kk * 32 + q * 8 + j) * kT + m];
                    short h, l; split_bf16(x, h, l);
                    Ahi[mt][kk][j] = h;
                    Alo[mt][kk][j] = l;
                }
            }
        }
    }

    // ---- GEMM: each wave owns 8 n-tiles, processed in pairs (4 indep chains) ----
#pragma unroll
    for (int np = 0; np < 4; ++np) {
        const int ntA = wave * 8 + np * 2;
        const int ntB = ntA + 1;
        f32x4 accA0 = {0.f, 0.f, 0.f, 0.f}, accA1 = {0.f, 0.f, 0.f, 0.f};
        f32x4 accB0 = {0.f, 0.f, 0.f, 0.f}, accB1 = {0.f, 0.f, 0.f, 0.f};
#pragma unroll
        for (int kk = 0; kk < 4; ++kk) {
            const int baseA = ((ntA * 4 + kk) * 64 + lane) * 8;
            const int baseB = ((ntB * 4 + kk) * 64 + lane) * 8;
            bf16x8 BhA = *(const bf16x8*)(Bhi + baseA);
            bf16x8 BlA = *(const bf16x8*)(Blo + baseA);
            bf16x8 BhB = *(const bf16x8*)(Bhi + baseB);
            bf16x8 BlB = *(const bf16x8*)(Blo + baseB);
            // hi*hi
            accA0 = __builtin_amdgcn_mfma_f32_16x16x32_bf16(Ahi[0][kk], BhA, accA0, 0, 0, 0);
            accA1 = __builtin_amdgcn_mfma_f32_16x16x32_bf16(Ahi[1][kk], BhA, accA1, 0, 0, 0);
            accB0 = __builtin_amdgcn_mfma_f32_16x16x32_bf16(Ahi[0][kk], BhB, accB0, 0, 0, 0);
            accB1 = __builtin_amdgcn_mfma_f32_16x16x32_bf16(Ahi[1][kk], BhB, accB1, 0, 0, 0);
            // lo*hi
            accA0 = __builtin_amdgcn_mfma_f32_16x16x32_bf16(Alo[0][kk], BhA, accA0, 0, 0, 0);
            accA1 = __builtin_amdgcn_mfma_f32_16x16x32_bf16(Alo[1][kk], BhA, accA1, 0, 0, 0);
            accB0 = __builtin_amdgcn_mfma_f32_16x16x32_bf16(Alo[0][kk], BhB, accB0, 0, 0, 0);
            accB1 = __builtin_amdgcn_mfma_f32_16x16x32_bf16(Alo[1][kk], BhB, accB1, 0, 0, 0);
            // hi*lo
            accA0 = __builtin_amdgcn_mfma_f32_16x16x32_bf16(Ahi[0][kk], BlA, accA0, 0, 0, 0);
            accA1 = __builtin_amdgcn_mfma_f32_16x16x32_bf16(Ahi[1][kk], BlA, accA1, 0, 0, 0);
            accB0 = __builtin_amdgcn_mfma_f32_16x16x32_bf16(Ahi[0][kk], BlB, accB0, 0, 0, 0);
            accB1 = __builtin_amdgcn_mfma_f32_16x16x32_bf16(Ahi[1][kk], BlB, accB1, 0, 0, 0);
        }
        // logits: D layout col=lane&15, row=q*4+r.  logit = 2*cross - m2[s]
        const float m2A = m2[ntA * 16 + nl];
        const float m2B = m2[ntB * 16 + nl];
#pragma unroll
        for (int r = 0; r < 4; ++r) {
            Ls[q * 4 + r     ][ntA * 16 + nl] = fmaf(2.f, accA0[r], -m2A);
            Ls[q * 4 + r + 16][ntA * 16 + nl] = fmaf(2.f, accA1[r], -m2A);
            Ls[q * 4 + r     ][ntB * 16 + nl] = fmaf(2.f, accB0[r], -m2B);
            Ls[q * 4 + r + 16][ntB * 16 + nl] = fmaf(2.f, accB1[r], -m2B);
        }
    }
    __syncthreads();

    // ---- softmax over s=512 per row: r = tid&31 row, jc = tid>>5 chunk of 64 ----
    const int r  = tid & 31;
    const int jc = tid >> 5;
    float* Lrow = &Ls[r][jc * 64];
    float mx = -3.0e38f;
#pragma unroll 8
    for (int k = 0; k < 64; ++k) mx = fmaxf(mx, Lrow[k]);
    red[jc * 32 + r] = mx;
    __syncthreads();
    if (tid < 32) {
        float m = red[tid];
#pragma unroll
        for (int k = 1; k < 8; ++k) m = fmaxf(m, red[k * 32 + tid]);
        rowM[tid] = m;
    }
    __syncthreads();
    const float M = rowM[r];
    float ssum = 0.f;
#pragma unroll 4
    for (int k = 0; k < 64; ++k) {
        float e = __expf(Lrow[k] - M);
        Lrow[k] = e;
        ssum += e;
    }
    red[jc * 32 + r] = ssum;
    __syncthreads();
    if (tid < 32) {
        float s = 0.f;
#pragma unroll
        for (int k = 0; k < 8; ++k) s += red[k * 32 + tid];
        rowInv[tid] = 1.f / s;
    }
    __syncthreads();

    // ---- transposed write: out[b][s][t0+i], f32x4 over i, nontemporal ----
    const int i4    = (tid & 7) * 4;     // i base 0..28
    const int sBase = tid >> 3;          // 0..31
    const float inv0 = rowInv[i4 + 0];
    const float inv1 = rowInv[i4 + 1];
    const float inv2 = rowInv[i4 + 2];
    const float inv3 = rowInv[i4 + 3];
    float* outB = out + ((size_t)b * kS) * kT + t0;
#pragma unroll
    for (int w = 0; w < 16; ++w) {
        int s = sBase + w * 32;
        f32x4 v;
        v[0] = Ls[i4 + 0][s] * inv0;
        v[1] = Ls[i4 + 1][s] * inv1;
        v[2] = Ls[i4 + 2][s] * inv2;
        v[3] = Ls[i4 + 3][s] * inv3;
        __builtin_nontemporal_store(v, (f32x4*)(outB + (size_t)s * kT + i4));
    }
}

extern "C" void kernel_launch(void* const* d_in, const int* in_sizes, int n_in,
                              void* d_out, int out_size, void* d_ws, size_t ws_size,
                              hipStream_t stream) {
    const float* H     = (const float*)d_in[0];
    const float* units = (const float*)d_in[1];
    float* out = (float*)d_out;

    char* ws = (char*)d_ws;
    short* Bhi = (short*)ws;                      // 32*4*64*8 = 65536 shorts (128 KB)
    short* Blo = (short*)(ws + 131072);           // 128 KB
    float* m2  = (float*)(ws + 262144);           // 2 KB

    prep_kernel<<<dim3(257), dim3(256), 0, stream>>>(units, Bhi, Blo, m2);
    dim3 grid(kT / kMT, kB);                      // 128 x 32 = 4096 blocks
    mb_mfma<<<grid, dim3(256), 0, stream>>>(H, Bhi, Blo, m2, out);
}